// Round 19
// baseline (114.196 us; speedup 1.0000x reference)
//
#include <hip/hip_runtime.h>
#include <hip/hip_bf16.h>
#include <math.h>

#define BB 2
#define SS 1024
#define DD 1024
#define HH 16
#define HD 64
#define BH (BB*HH)

typedef __attribute__((ext_vector_type(8))) short short8_t;
typedef __attribute__((ext_vector_type(4))) float f32x4;

#if __has_builtin(__builtin_amdgcn_exp2f)
#define EXP2(x) __builtin_amdgcn_exp2f(x)
#else
#define EXP2(x) exp2f(x)
#endif

__device__ __forceinline__ ushort f2bf(float f) {
    union { float f; unsigned u; } a; a.f = f;
    unsigned u = a.u;
    u += 0x7FFFu + ((u >> 16) & 1u);   // RNE
    return (ushort)(u >> 16);
}
__device__ __forceinline__ float bf2f(ushort b) {
    union { unsigned u; float f; } a; a.u = ((unsigned)b) << 16;
    return a.f;
}
// packed f32x2 -> bf16x2 (RNE), low = a
__device__ __forceinline__ unsigned pkbf(float a, float b) {
    unsigned r;
    asm("v_cvt_pk_bf16_f32 %0, %1, %2" : "=v"(r) : "v"(a), "v"(b));
    return r;
}

// ---------------- fp32 -> bf16 conversion, all 5 tensors in one launch ----------------
__global__ __launch_bounds__(256) void cvt_all_kernel(
    const float* __restrict__ x,  const float* __restrict__ wq,
    const float* __restrict__ wk, const float* __restrict__ wv,
    const float* __restrict__ wo,
    ushort* __restrict__ xb,  ushort* __restrict__ wqb, ushort* __restrict__ wkb,
    ushort* __restrict__ wvb, ushort* __restrict__ wob)
{
    int bid = blockIdx.x;
    const float* src; ushort* dst; int off;
    if (bid < 2048) { src = x; dst = xb; off = bid; }
    else {
        int seg = (bid - 2048) >> 10;
        off = (bid - 2048) & 1023;
        if (seg == 0)      { src = wq; dst = wqb; }
        else if (seg == 1) { src = wk; dst = wkb; }
        else if (seg == 2) { src = wv; dst = wvb; }
        else               { src = wo; dst = wob; }
    }
    int i = (off * 256 + threadIdx.x) * 4;
    float4 v = *reinterpret_cast<const float4*>(src + i);
    ushort4 o;
    o.x = f2bf(v.x); o.y = f2bf(v.y); o.z = f2bf(v.z); o.w = f2bf(v.w);
    *reinterpret_cast<ushort4*>(dst + i) = o;
}

// ---------------- fused QKV GEMM: one block computes 64x64 of Q, K, V ----------------
__global__ __launch_bounds__(256) void gemm_qkv_fused(
    const ushort* __restrict__ xb,
    const ushort* __restrict__ wq, const ushort* __restrict__ wk, const ushort* __restrict__ wv,
    const float* __restrict__ bq, const float* __restrict__ bk, const float* __restrict__ bvp,
    ushort* __restrict__ Qb, ushort* __restrict__ Kh, ushort* __restrict__ Vt2,
    const float* __restrict__ pf, float* __restrict__ E1, float* __restrict__ E3,
    float qscale, float a1, float a3)
{
    constexpr int BK = 32;
    __shared__ ushort lsa[64 * BK];        // 4KB
    __shared__ ushort lsb[3][64 * BK];     // 12KB
    __shared__ float rkbuf[2][64];
    const int tid  = threadIdx.x;
    const int lane = tid & 63;
    const int wave = tid >> 6;
    const int wrow = (wave >> 1) * 32;
    const int wcol = (wave & 1) * 32;
    const int tileM = blockIdx.y * 64;
    const int tileN = blockIdx.x * 64;
    const int fr  = lane & 15;
    const int fks = (lane >> 4) * 8;
    const int l4  = lane >> 2;
    const int lm4 = lane & 3;
    f32x4 acc[3][2][2] = {};

    const ushort* src = (wave == 0) ? xb : ((wave == 1) ? wq : ((wave == 2) ? wk : wv));
    const int srow = (wave == 0) ? tileM : tileN;
    ushort* ldst = (wave == 0) ? lsa : lsb[wave - 1];

    for (int kb = 0; kb < DD; kb += BK) {
        __syncthreads();
        #pragma unroll
        for (int i = 0; i < 4; ++i) {
            const ushort* g = src + (size_t)(srow + i * 16 + l4) * DD + kb + lm4 * 8;
            __builtin_amdgcn_global_load_lds(
                (const __attribute__((address_space(1))) unsigned*)g,
                (__attribute__((address_space(3))) unsigned*)&ldst[i * 512], 16, 0, 0);
        }
        __syncthreads();
        short8_t af[2];
        #pragma unroll
        for (int r = 0; r < 2; ++r)
            af[r] = *reinterpret_cast<const short8_t*>(&lsa[(wrow + r * 16 + fr) * BK + fks]);
        #pragma unroll
        for (int t = 0; t < 3; ++t) {
            #pragma unroll
            for (int c = 0; c < 2; ++c) {
                short8_t bfg = *reinterpret_cast<const short8_t*>(
                    &lsb[t][(wcol + c * 16 + fr) * BK + fks]);
                #pragma unroll
                for (int r = 0; r < 2; ++r)
                    acc[t][r][c] = __builtin_amdgcn_mfma_f32_16x16x32_bf16(af[r], bfg, acc[t][r][c], 0, 0, 0);
            }
        }
    }

    const int rr = (lane >> 4) * 4;
    const int b  = tileM >> 10;
    const int h  = (tileN >> 6) & 15;
    const int bh = b * 16 + h;

    // Q epilogue (row-major, pre-scaled)
    #pragma unroll
    for (int r = 0; r < 2; ++r)
        #pragma unroll
        for (int c = 0; c < 2; ++c) {
            int n = tileN + wcol + c * 16 + fr;
            float bb = bq[n];
            #pragma unroll
            for (int q = 0; q < 4; ++q) {
                int m = tileM + wrow + r * 16 + rr + q;
                Qb[(size_t)m * DD + n] = f2bf((acc[0][r][c][q] + bb) * qscale);
            }
        }

    // K epilogue (head-major Kh) + rk partials
    float rkp[2][4] = {};
    #pragma unroll
    for (int r = 0; r < 2; ++r)
        #pragma unroll
        for (int c = 0; c < 2; ++c) {
            int n = tileN + wcol + c * 16 + fr;
            float bb = bk[n];
            int d = n & 63;
            #pragma unroll
            for (int q = 0; q < 4; ++q) {
                int m = tileM + wrow + r * 16 + rr + q;
                float v = acc[1][r][c][q] + bb;
                rkp[r][q] += v;
                Kh[((size_t)bh * 1024 + (m & 1023)) * 64 + d] = f2bf(v);
            }
        }
    #pragma unroll
    for (int r = 0; r < 2; ++r)
        #pragma unroll
        for (int q = 0; q < 4; ++q) {
            float s = rkp[r][q];
            s += __shfl_xor(s, 1);
            s += __shfl_xor(s, 2);
            s += __shfl_xor(s, 4);
            s += __shfl_xor(s, 8);
            if (fr == 0) rkbuf[wave & 1][wrow + r * 16 + rr + q] = s;
        }

    // V epilogue (k-tiled Vt2)
    #pragma unroll
    for (int r = 0; r < 2; ++r)
        #pragma unroll
        for (int c = 0; c < 2; ++c) {
            int n = tileN + wcol + c * 16 + fr;
            float bb = bvp[n];
            int d = n & 63;
            #pragma unroll
            for (int q = 0; q < 4; ++q) {
                int m = tileM + wrow + r * 16 + rr + q;
                int j = m & 1023;
                Vt2[((size_t)(bh * 32 + (j >> 5)) * 64 + d) * 32 + (j & 31)] =
                    f2bf(acc[2][r][c][q] + bb);
            }
        }

    __syncthreads();
    if (tid < 64) {
        float rk = rkbuf[0][tid] + rkbuf[1][tid];
        int m = tileM + tid;
        int idx = bh * 1024 + (m & 1023);
        float p = pf[h];
        E1[idx] = __expf(a1 * p * rk);
        E3[idx] = __expf(a3 * p * rk);
    }
}

// ---------------- bf16 GEMM (m97 structure) for the output projection ----------------
template<int BM, int BN>
__device__ __forceinline__ void gemm_out_body(
    const ushort* __restrict__ A, const ushort* __restrict__ Bm,
    const float* __restrict__ bias, float* __restrict__ Cout, int N, int K)
{
    constexpr int BK = 32;
    __shared__ ushort lsa[BM * BK];
    __shared__ ushort lsb[BN * BK];
    const int tid  = threadIdx.x;
    const int lane = tid & 63;
    const int wave = tid >> 6;
    constexpr int RI = BM / 32;
    constexpr int CI = BN / 32;
    constexpr int ACH = BM / 16;
    constexpr int TCH = ACH + BN / 16;
    const int wrow = (wave >> 1) * (BM / 2);
    const int wcol = (wave & 1) * (BN / 2);
    const int tileM = blockIdx.y * BM;
    const int tileN = blockIdx.x * BN;
    const int fr  = lane & 15;
    const int fks = (lane >> 4) * 8;
    const int l4  = lane >> 2;
    const int lm4 = lane & 3;
    f32x4 acc[RI][CI] = {};

    for (int kb = 0; kb < K; kb += BK) {
        __syncthreads();
        #pragma unroll
        for (int i = 0; i < TCH / 4; ++i) {
            int chunk = wave * (TCH / 4) + i;
            if (chunk < ACH) {
                const ushort* g = A + (size_t)(tileM + chunk * 16 + l4) * K + kb + lm4 * 8;
                __builtin_amdgcn_global_load_lds(
                    (const __attribute__((address_space(1))) unsigned*)g,
                    (__attribute__((address_space(3))) unsigned*)&lsa[chunk * 512], 16, 0, 0);
            } else {
                int bc = chunk - ACH;
                const ushort* g = Bm + (size_t)(tileN + bc * 16 + l4) * K + kb + lm4 * 8;
                __builtin_amdgcn_global_load_lds(
                    (const __attribute__((address_space(1))) unsigned*)g,
                    (__attribute__((address_space(3))) unsigned*)&lsb[bc * 512], 16, 0, 0);
            }
        }
        __syncthreads();
        short8_t af[RI], bfg[CI];
        #pragma unroll
        for (int r = 0; r < RI; ++r)
            af[r] = *reinterpret_cast<const short8_t*>(&lsa[(wrow + r * 16 + fr) * BK + fks]);
        #pragma unroll
        for (int c = 0; c < CI; ++c)
            bfg[c] = *reinterpret_cast<const short8_t*>(&lsb[(wcol + c * 16 + fr) * BK + fks]);
        #pragma unroll
        for (int r = 0; r < RI; ++r)
            #pragma unroll
            for (int c = 0; c < CI; ++c)
                acc[r][c] = __builtin_amdgcn_mfma_f32_16x16x32_bf16(af[r], bfg[c], acc[r][c], 0, 0, 0);
    }

    const int rr = (lane >> 4) * 4;
    #pragma unroll
    for (int r = 0; r < RI; ++r)
        #pragma unroll
        for (int c = 0; c < CI; ++c) {
            int n = tileN + wcol + c * 16 + fr;
            float bb = bias[n];
            #pragma unroll
            for (int q = 0; q < 4; ++q) {
                int m = tileM + wrow + r * 16 + rr + q;
                Cout[(size_t)m * N + n] = acc[r][c][q] + bb;
            }
        }
}

__global__ __launch_bounds__(256) void gemm_out_kernel(
    const ushort* __restrict__ ctxb, const ushort* __restrict__ wo,
    const float* __restrict__ bo, float* __restrict__ out)
{
    gemm_out_body<64, 64>(ctxb, wo, bo, out, DD, DD);
}

// ---------------- two-pass attention, 32 q-rows/block, NO y-cache (recompute) ----------------
// Pass A: l_t only (C-layout, scalar E per subtile, zero LDS) -> LDS drops 69.6->36.9KB
// -> 4 blocks/CU (2x occupancy). Pass B: recompute QK (K L2-hot contiguous), f32 score
// transpose through sbuf (R5-validated same-wave pattern), normalized P, shared-V PV.
// y from f32 scores (more accurate than R14's bf16 cache).
__global__ __launch_bounds__(256) void attn_kernel(
    const ushort* __restrict__ Qb, const ushort* __restrict__ Kh,
    const ushort* __restrict__ Vt2, const float* __restrict__ E1,
    const float* __restrict__ E3, ushort* __restrict__ ctxb)
{
    __shared__ float sbuf[4][32][68];   // per-wave score transpose; reused as ctx partials
    __shared__ float lbuf[4][4][32];    // [wave][t][qrow 0..31]
    const int wg  = blockIdx.x;
    const int swz = (wg & 7) * 128 + (wg >> 3);   // XCD swizzle (1024 % 8 == 0)
    const int bh  = swz >> 5;
    const int qb  = (swz & 31) * 32;              // 32-row q-block
    const int b = bh >> 4, h = bh & 15;
    const int wave = threadIdx.x >> 6;
    const int lane = threadIdx.x & 63;
    const int fr = lane & 15;
    const int g  = lane >> 4;
    const int fk = g * 8;

    const float wt[4] = {0.008f, 0.032f, 0.16f, 0.8f};   // momentum-collapsed weights

    // Q A-fragments for both 16-row tiles (pre-scaled)
    const ushort* qbase0 = Qb + (size_t)(b * SS + qb + fr) * DD + h * HD;
    const ushort* qbase1 = Qb + (size_t)(b * SS + qb + 16 + fr) * DD + h * HD;
    const short8_t aq0a = *reinterpret_cast<const short8_t*>(qbase0 + fk);
    const short8_t aq1a = *reinterpret_cast<const short8_t*>(qbase0 + 32 + fk);
    const short8_t aq0b = *reinterpret_cast<const short8_t*>(qbase1 + fk);
    const short8_t aq1b = *reinterpret_cast<const short8_t*>(qbase1 + 32 + fk);

    const float* e1h = E1 + bh * SS;
    const float* e3h = E3 + bh * SS;
    const ushort* khead = Kh + (size_t)bh * SS * HD;
    const ushort* vhead = Vt2 + (size_t)bh * (SS / 32) * HD * 32;

    // ---- pass A: denominators only (C-layout; no LDS) ----
    float lA[4][4] = {}, lB[4][4] = {};
    for (int it = 0; it < 4; ++it) {
        const int k0 = wave * 256 + it * 64;
        #pragma unroll
        for (int n = 0; n < 4; ++n) {
            const ushort* kb = khead + (size_t)(k0 + n * 16 + fr) * HD;
            short8_t bk0 = *reinterpret_cast<const short8_t*>(kb + fk);
            short8_t bk1 = *reinterpret_cast<const short8_t*>(kb + 32 + fk);
            f32x4 za = {0.f, 0.f, 0.f, 0.f};
            f32x4 zb = {0.f, 0.f, 0.f, 0.f};
            za = __builtin_amdgcn_mfma_f32_16x16x32_bf16(aq0a, bk0, za, 0, 0, 0);
            za = __builtin_amdgcn_mfma_f32_16x16x32_bf16(aq1a, bk1, za, 0, 0, 0);
            zb = __builtin_amdgcn_mfma_f32_16x16x32_bf16(aq0b, bk0, zb, 0, 0, 0);
            zb = __builtin_amdgcn_mfma_f32_16x16x32_bf16(aq1b, bk1, zb, 0, 0, 0);
            float e1v = e1h[k0 + n * 16 + fr];
            float e3v = e3h[k0 + n * 16 + fr];
            #pragma unroll
            for (int r = 0; r < 4; ++r) {
                float ya  = EXP2(za[r]);
                float ya2 = ya * ya;
                float ya4 = ya2 * ya2;
                float ya6 = ya4 * ya2;
                lA[0][r] += ya4;
                lA[1][r] += ya4 * ya * e1v;
                lA[2][r] += ya6;
                lA[3][r] += ya6 * ya * e3v;
                float yb  = EXP2(zb[r]);
                float yb2 = yb * yb;
                float yb4 = yb2 * yb2;
                float yb6 = yb4 * yb2;
                lB[0][r] += yb4;
                lB[1][r] += yb4 * yb * e1v;
                lB[2][r] += yb6;
                lB[3][r] += yb6 * yb * e3v;
            }
        }
    }
    // reduce across the 16 k-col lanes (lane bits 0..3)
    #pragma unroll
    for (int t = 0; t < 4; ++t)
        #pragma unroll
        for (int r = 0; r < 4; ++r) {
            float sa = lA[t][r];
            sa += __shfl_xor(sa, 1);
            sa += __shfl_xor(sa, 2);
            sa += __shfl_xor(sa, 4);
            sa += __shfl_xor(sa, 8);
            lA[t][r] = sa;
            float sb = lB[t][r];
            sb += __shfl_xor(sb, 1);
            sb += __shfl_xor(sb, 2);
            sb += __shfl_xor(sb, 4);
            sb += __shfl_xor(sb, 8);
            lB[t][r] = sb;
        }
    if (fr == 0) {
        #pragma unroll
        for (int t = 0; t < 4; ++t)
            #pragma unroll
            for (int r = 0; r < 4; ++r) {
                lbuf[wave][t][g * 4 + r]      = lA[t][r];
                lbuf[wave][t][16 + g * 4 + r] = lB[t][r];
            }
    }
    __syncthreads();

    // per-lane normalized weights for A-frag q-rows fr (tile0) and 16+fr (tile1)
    float wlA[4], wlB[4];
    #pragma unroll
    for (int t = 0; t < 4; ++t) {
        float sa = lbuf[0][t][fr] + lbuf[1][t][fr] + lbuf[2][t][fr] + lbuf[3][t][fr];
        float sb = lbuf[0][t][16 + fr] + lbuf[1][t][16 + fr] + lbuf[2][t][16 + fr] + lbuf[3][t][16 + fr];
        wlA[t] = wt[t] / sa;
        wlB[t] = wt[t] / sb;
    }

    // ---- pass B: recompute QK, f32 transpose, normalized P, shared-V PV ----
    f32x4 caccA[4] = {}, caccB[4] = {};
    union FragU { short8_t s; unsigned u[4]; };
    for (int it = 0; it < 4; ++it) {
        const int k0 = wave * 256 + it * 64;
        #pragma unroll
        for (int n = 0; n < 4; ++n) {
            const ushort* kb = khead + (size_t)(k0 + n * 16 + fr) * HD;
            short8_t bk0 = *reinterpret_cast<const short8_t*>(kb + fk);
            short8_t bk1 = *reinterpret_cast<const short8_t*>(kb + 32 + fk);
            f32x4 za = {0.f, 0.f, 0.f, 0.f};
            f32x4 zb = {0.f, 0.f, 0.f, 0.f};
            za = __builtin_amdgcn_mfma_f32_16x16x32_bf16(aq0a, bk0, za, 0, 0, 0);
            za = __builtin_amdgcn_mfma_f32_16x16x32_bf16(aq1a, bk1, za, 0, 0, 0);
            zb = __builtin_amdgcn_mfma_f32_16x16x32_bf16(aq0b, bk0, zb, 0, 0, 0);
            zb = __builtin_amdgcn_mfma_f32_16x16x32_bf16(aq1b, bk1, zb, 0, 0, 0);
            #pragma unroll
            for (int r = 0; r < 4; ++r) {
                sbuf[wave][g * 4 + r][n * 16 + fr]      = za[r];
                sbuf[wave][16 + g * 4 + r][n * 16 + fr] = zb[r];
            }
        }
        // transposed reads (same-wave DS in-order; compiler tracks dependency)
        #pragma unroll
        for (int half = 0; half < 2; ++half) {
            f32x4 sa0 = *reinterpret_cast<f32x4*>(&sbuf[wave][fr][half * 32 + fk]);
            f32x4 sa1 = *reinterpret_cast<f32x4*>(&sbuf[wave][fr][half * 32 + fk + 4]);
            f32x4 sb0 = *reinterpret_cast<f32x4*>(&sbuf[wave][16 + fr][half * 32 + fk]);
            f32x4 sb1 = *reinterpret_cast<f32x4*>(&sbuf[wave][16 + fr][half * 32 + fk + 4]);
            const float* e1p = e1h + k0 + half * 32 + fk;
            const float* e3p = e3h + k0 + half * 32 + fk;
            float4 e1a = *reinterpret_cast<const float4*>(e1p);
            float4 e1b = *reinterpret_cast<const float4*>(e1p + 4);
            float4 e3a = *reinterpret_cast<const float4*>(e3p);
            float4 e3b = *reinterpret_cast<const float4*>(e3p + 4);
            FragU paA, paB;
            #pragma unroll
            for (int i = 0; i < 4; ++i) {
                float pva[2], pvb[2];
                #pragma unroll
                for (int j = 0; j < 2; ++j) {
                    const int e = 2 * i + j;
                    float e1v = (e < 4) ? ((const float*)&e1a)[e] : ((const float*)&e1b)[e - 4];
                    float e3v = (e < 4) ? ((const float*)&e3a)[e] : ((const float*)&e3b)[e - 4];
                    float saV = (e < 4) ? sa0[e] : sa1[e - 4];
                    float sbV = (e < 4) ? sb0[e] : sb1[e - 4];
                    float ya  = EXP2(saV);
                    float ya2 = ya * ya;
                    float ya4 = ya2 * ya2;
                    float t1a = fmaf(ya, wlA[1] * e1v, wlA[0]);
                    float t2a = fmaf(ya, wlA[3] * e3v, wlA[2]);
                    pva[j] = ya4 * fmaf(ya2, t2a, t1a);
                    float yb  = EXP2(sbV);
                    float yb2 = yb * yb;
                    float yb4 = yb2 * yb2;
                    float t1b = fmaf(yb, wlB[1] * e1v, wlB[0]);
                    float t2b = fmaf(yb, wlB[3] * e3v, wlB[2]);
                    pvb[j] = yb4 * fmaf(yb2, t2b, t1b);
                }
                paA.u[i] = pkbf(pva[0], pva[1]);
                paB.u[i] = pkbf(pvb[0], pvb[1]);
            }
            const ushort* vt = vhead + (size_t)((k0 + half * 32) >> 5) * HD * 32;
            #pragma unroll
            for (int n2 = 0; n2 < 4; ++n2) {
                short8_t v = *reinterpret_cast<const short8_t*>(
                    vt + (n2 * 16 + fr) * 32 + fk);
                caccA[n2] = __builtin_amdgcn_mfma_f32_16x16x32_bf16(paA.s, v, caccA[n2], 0, 0, 0);
                caccB[n2] = __builtin_amdgcn_mfma_f32_16x16x32_bf16(paB.s, v, caccB[n2], 0, 0, 0);
            }
        }
    }

    // ---- epilogue: per-wave partials -> cross-wave sum, both tiles ----
    float* ctxp = &sbuf[wave][0][0];   // own region; own pass-B reads are done (in-order)
    #pragma unroll
    for (int n2 = 0; n2 < 4; ++n2)
        #pragma unroll
        for (int q = 0; q < 4; ++q) {
            ctxp[(g * 4 + q) * 68 + n2 * 16 + fr]      = caccA[n2][q];
            ctxp[(16 + g * 4 + q) * 68 + n2 * 16 + fr] = caccB[n2][q];
        }
    __syncthreads();

    const int d0 = (threadIdx.x & 15) * 4;
    float* base = &sbuf[0][0][0];      // wave stride = 32*68 = 2176 f32
    #pragma unroll
    for (int rr = 0; rr < 2; ++rr) {
        int row = rr * 16 + (threadIdx.x >> 4);
        float4 s0 = *reinterpret_cast<float4*>(base + 0 * 2176 + row * 68 + d0);
        float4 s1 = *reinterpret_cast<float4*>(base + 1 * 2176 + row * 68 + d0);
        float4 s2 = *reinterpret_cast<float4*>(base + 2 * 2176 + row * 68 + d0);
        float4 s3 = *reinterpret_cast<float4*>(base + 3 * 2176 + row * 68 + d0);
        float ox = s0.x + s1.x + s2.x + s3.x;
        float oy = s0.y + s1.y + s2.y + s3.y;
        float oz = s0.z + s1.z + s2.z + s3.z;
        float ow = s0.w + s1.w + s2.w + s3.w;
        uint2 o;
        o.x = pkbf(ox, oy);
        o.y = pkbf(oz, ow);
        size_t off = (size_t)(b * SS + qb + row) * DD + h * HD + d0;
        *reinterpret_cast<uint2*>(ctxb + off) = o;
    }
}

// ---------------- launch ----------------
extern "C" void kernel_launch(void* const* d_in, const int* in_sizes, int n_in,
                              void* d_out, int out_size, void* d_ws, size_t ws_size,
                              hipStream_t stream) {
    const float* x  = (const float*)d_in[0];
    const float* Wq = (const float*)d_in[1];
    const float* bq = (const float*)d_in[2];
    const float* Wk = (const float*)d_in[3];
    const float* bk = (const float*)d_in[4];
    const float* Wv = (const float*)d_in[5];
    const float* bv = (const float*)d_in[6];
    const float* Wo = (const float*)d_in[7];
    const float* bo = (const float*)d_in[8];
    // d_in[9] resonance_bias: per-head row-constant -> cancels in softmax
    const float* pf = (const float*)d_in[10];

    // workspace layout (~28.3 MB)
    ushort* xb   = (ushort*)d_ws;
    ushort* wqb  = xb  + (size_t)2 * 1024 * 1024;
    ushort* wkb  = wqb + (size_t)1024 * 1024;
    ushort* wvb  = wkb + (size_t)1024 * 1024;
    ushort* wob  = wvb + (size_t)1024 * 1024;
    ushort* Qb   = wob + (size_t)1024 * 1024;
    ushort* Kh   = Qb  + (size_t)2 * 1024 * 1024;   // head-major K [bh][j][d]
    ushort* Vt2  = Kh  + (size_t)2 * 1024 * 1024;   // k-tiled V  [bh][j/32][d][j%32]
    ushort* ctxb = Vt2 + (size_t)2 * 1024 * 1024;
    float*  E1p  = (float*)(ctxb + (size_t)2 * 1024 * 1024);
    float*  E3p  = E1p + (size_t)BH * SS;

    // per-iteration constants (match reference f32 casting)
    float ph[4], ctv[4];
    for (int t = 0; t < 4; ++t) {
        double tn = (double)t / 4.0;
        ph[t]  = sinf((float)(2.0 * tn * M_PI + 0.0));
        ctv[t] = (float)((0.8 + 0.2 * (double)t) * 0.125);  // beta_t / sqrt(HD)
    }
    const double LOG2E = 1.44269504088896340736;
    float qscale = (float)(0.025 * LOG2E);  // Q pre-scale: S' = 0.025*log2e*S
    float a1 = ctv[1] * ph[1];   // c1 * sin(pi/2)
    float a3 = ctv[3] * ph[3];   // c3 * sin(3pi/2)

    cvt_all_kernel<<<6144, 256, 0, stream>>>(x, Wq, Wk, Wv, Wo, xb, wqb, wkb, wvb, wob);

    gemm_qkv_fused<<<dim3(16, 32), 256, 0, stream>>>(xb, wqb, wkb, wvb, bq, bk, bv,
                                                     Qb, Kh, Vt2, pf, E1p, E3p,
                                                     qscale, a1, a3);

    attn_kernel<<<1024, 256, 0, stream>>>(Qb, Kh, Vt2, E1p, E3p, ctxb);

    gemm_out_kernel<<<dim3(16, 32), 256, 0, stream>>>(ctxb, wob, bo, (float*)d_out);
}

// Round 20
// 97.523 us; speedup vs baseline: 1.1710x; 1.1710x over previous
//
#include <hip/hip_runtime.h>
#include <hip/hip_bf16.h>
#include <math.h>

#define BB 2
#define SS 1024
#define DD 1024
#define HH 16
#define HD 64
#define BH (BB*HH)

typedef __attribute__((ext_vector_type(8))) short short8_t;
typedef __attribute__((ext_vector_type(4))) float f32x4;

#if __has_builtin(__builtin_amdgcn_exp2f)
#define EXP2(x) __builtin_amdgcn_exp2f(x)
#else
#define EXP2(x) exp2f(x)
#endif

__device__ __forceinline__ ushort f2bf(float f) {
    union { float f; unsigned u; } a; a.f = f;
    unsigned u = a.u;
    u += 0x7FFFu + ((u >> 16) & 1u);   // RNE
    return (ushort)(u >> 16);
}
__device__ __forceinline__ float bf2f(ushort b) {
    union { unsigned u; float f; } a; a.u = ((unsigned)b) << 16;
    return a.f;
}
// packed f32x2 -> bf16x2 (RNE), low = a
__device__ __forceinline__ unsigned pkbf(float a, float b) {
    unsigned r;
    asm("v_cvt_pk_bf16_f32 %0, %1, %2" : "=v"(r) : "v"(a), "v"(b));
    return r;
}

// ---------------- fp32 -> bf16 conversion, all 5 tensors in one launch ----------------
__global__ __launch_bounds__(256) void cvt_all_kernel(
    const float* __restrict__ x,  const float* __restrict__ wq,
    const float* __restrict__ wk, const float* __restrict__ wv,
    const float* __restrict__ wo,
    ushort* __restrict__ xb,  ushort* __restrict__ wqb, ushort* __restrict__ wkb,
    ushort* __restrict__ wvb, ushort* __restrict__ wob)
{
    int bid = blockIdx.x;
    const float* src; ushort* dst; int off;
    if (bid < 2048) { src = x; dst = xb; off = bid; }
    else {
        int seg = (bid - 2048) >> 10;
        off = (bid - 2048) & 1023;
        if (seg == 0)      { src = wq; dst = wqb; }
        else if (seg == 1) { src = wk; dst = wkb; }
        else if (seg == 2) { src = wv; dst = wvb; }
        else               { src = wo; dst = wob; }
    }
    int i = (off * 256 + threadIdx.x) * 4;
    float4 v = *reinterpret_cast<const float4*>(src + i);
    ushort4 o;
    o.x = f2bf(v.x); o.y = f2bf(v.y); o.z = f2bf(v.z); o.w = f2bf(v.w);
    *reinterpret_cast<ushort4*>(dst + i) = o;
}

// ---------------- fused QKV GEMM: one block computes 64x64 of Q, K, V ----------------
// A-tile staged ONCE per K-step; 12 MFMAs/step (3x density of split version).
// Epilogues: Q row-major (pre-scaled), K head-major Kh + fused E1/E3 tables
// (rk via cross-wave LDS reduce), V k-tiled Vt2.
__global__ __launch_bounds__(256) void gemm_qkv_fused(
    const ushort* __restrict__ xb,
    const ushort* __restrict__ wq, const ushort* __restrict__ wk, const ushort* __restrict__ wv,
    const float* __restrict__ bq, const float* __restrict__ bk, const float* __restrict__ bvp,
    ushort* __restrict__ Qb, ushort* __restrict__ Kh, ushort* __restrict__ Vt2,
    const float* __restrict__ pf, float* __restrict__ E1, float* __restrict__ E3,
    float qscale, float a1, float a3)
{
    constexpr int BK = 32;
    __shared__ ushort lsa[64 * BK];        // 4KB
    __shared__ ushort lsb[3][64 * BK];     // 12KB
    __shared__ float rkbuf[2][64];
    const int tid  = threadIdx.x;
    const int lane = tid & 63;
    const int wave = tid >> 6;
    const int wrow = (wave >> 1) * 32;
    const int wcol = (wave & 1) * 32;
    const int tileM = blockIdx.y * 64;
    const int tileN = blockIdx.x * 64;
    const int fr  = lane & 15;
    const int fks = (lane >> 4) * 8;
    const int l4  = lane >> 2;
    const int lm4 = lane & 3;
    f32x4 acc[3][2][2] = {};

    // wave 0 stages A; waves 1..3 stage B[wave-1]
    const ushort* src = (wave == 0) ? xb : ((wave == 1) ? wq : ((wave == 2) ? wk : wv));
    const int srow = (wave == 0) ? tileM : tileN;
    ushort* ldst = (wave == 0) ? lsa : lsb[wave - 1];

    for (int kb = 0; kb < DD; kb += BK) {
        __syncthreads();
        #pragma unroll
        for (int i = 0; i < 4; ++i) {
            const ushort* g = src + (size_t)(srow + i * 16 + l4) * DD + kb + lm4 * 8;
            __builtin_amdgcn_global_load_lds(
                (const __attribute__((address_space(1))) unsigned*)g,
                (__attribute__((address_space(3))) unsigned*)&ldst[i * 512], 16, 0, 0);
        }
        __syncthreads();
        short8_t af[2];
        #pragma unroll
        for (int r = 0; r < 2; ++r)
            af[r] = *reinterpret_cast<const short8_t*>(&lsa[(wrow + r * 16 + fr) * BK + fks]);
        #pragma unroll
        for (int t = 0; t < 3; ++t) {
            #pragma unroll
            for (int c = 0; c < 2; ++c) {
                short8_t bfg = *reinterpret_cast<const short8_t*>(
                    &lsb[t][(wcol + c * 16 + fr) * BK + fks]);
                #pragma unroll
                for (int r = 0; r < 2; ++r)
                    acc[t][r][c] = __builtin_amdgcn_mfma_f32_16x16x32_bf16(af[r], bfg, acc[t][r][c], 0, 0, 0);
            }
        }
    }

    const int rr = (lane >> 4) * 4;
    const int b  = tileM >> 10;
    const int h  = (tileN >> 6) & 15;
    const int bh = b * 16 + h;

    // ---- Q epilogue (row-major, pre-scaled) ----
    #pragma unroll
    for (int r = 0; r < 2; ++r)
        #pragma unroll
        for (int c = 0; c < 2; ++c) {
            int n = tileN + wcol + c * 16 + fr;
            float bb = bq[n];
            #pragma unroll
            for (int q = 0; q < 4; ++q) {
                int m = tileM + wrow + r * 16 + rr + q;
                Qb[(size_t)m * DD + n] = f2bf((acc[0][r][c][q] + bb) * qscale);
            }
        }

    // ---- K epilogue (head-major Kh) + rk partials ----
    float rkp[2][4] = {};
    #pragma unroll
    for (int r = 0; r < 2; ++r)
        #pragma unroll
        for (int c = 0; c < 2; ++c) {
            int n = tileN + wcol + c * 16 + fr;
            float bb = bk[n];
            int d = n & 63;
            #pragma unroll
            for (int q = 0; q < 4; ++q) {
                int m = tileM + wrow + r * 16 + rr + q;
                float v = acc[1][r][c][q] + bb;
                rkp[r][q] += v;
                Kh[((size_t)bh * 1024 + (m & 1023)) * 64 + d] = f2bf(v);
            }
        }
    #pragma unroll
    for (int r = 0; r < 2; ++r)
        #pragma unroll
        for (int q = 0; q < 4; ++q) {
            float s = rkp[r][q];
            s += __shfl_xor(s, 1);
            s += __shfl_xor(s, 2);
            s += __shfl_xor(s, 4);
            s += __shfl_xor(s, 8);
            if (fr == 0) rkbuf[wave & 1][wrow + r * 16 + rr + q] = s;
        }

    // ---- V epilogue (k-tiled Vt2) ----
    #pragma unroll
    for (int r = 0; r < 2; ++r)
        #pragma unroll
        for (int c = 0; c < 2; ++c) {
            int n = tileN + wcol + c * 16 + fr;
            float bb = bvp[n];
            int d = n & 63;
            #pragma unroll
            for (int q = 0; q < 4; ++q) {
                int m = tileM + wrow + r * 16 + rr + q;
                int j = m & 1023;
                Vt2[((size_t)(bh * 32 + (j >> 5)) * 64 + d) * 32 + (j & 31)] =
                    f2bf(acc[2][r][c][q] + bb);
            }
        }

    __syncthreads();
    // ---- fused E tables (first 64 threads; one head per block) ----
    if (tid < 64) {
        float rk = rkbuf[0][tid] + rkbuf[1][tid];
        int m = tileM + tid;
        int idx = bh * 1024 + (m & 1023);
        float p = pf[h];
        E1[idx] = __expf(a1 * p * rk);
        E3[idx] = __expf(a3 * p * rk);
    }
}

// ---------------- bf16 GEMM (m97 structure) for the output projection ----------------
template<int BM, int BN>
__device__ __forceinline__ void gemm_out_body(
    const ushort* __restrict__ A, const ushort* __restrict__ Bm,
    const float* __restrict__ bias, float* __restrict__ Cout, int N, int K)
{
    constexpr int BK = 32;
    __shared__ ushort lsa[BM * BK];
    __shared__ ushort lsb[BN * BK];
    const int tid  = threadIdx.x;
    const int lane = tid & 63;
    const int wave = tid >> 6;
    constexpr int RI = BM / 32;
    constexpr int CI = BN / 32;
    constexpr int ACH = BM / 16;
    constexpr int TCH = ACH + BN / 16;
    const int wrow = (wave >> 1) * (BM / 2);
    const int wcol = (wave & 1) * (BN / 2);
    const int tileM = blockIdx.y * BM;
    const int tileN = blockIdx.x * BN;
    const int fr  = lane & 15;
    const int fks = (lane >> 4) * 8;
    const int l4  = lane >> 2;
    const int lm4 = lane & 3;
    f32x4 acc[RI][CI] = {};

    for (int kb = 0; kb < K; kb += BK) {
        __syncthreads();
        #pragma unroll
        for (int i = 0; i < TCH / 4; ++i) {
            int chunk = wave * (TCH / 4) + i;
            if (chunk < ACH) {
                const ushort* g = A + (size_t)(tileM + chunk * 16 + l4) * K + kb + lm4 * 8;
                __builtin_amdgcn_global_load_lds(
                    (const __attribute__((address_space(1))) unsigned*)g,
                    (__attribute__((address_space(3))) unsigned*)&lsa[chunk * 512], 16, 0, 0);
            } else {
                int bc = chunk - ACH;
                const ushort* g = Bm + (size_t)(tileN + bc * 16 + l4) * K + kb + lm4 * 8;
                __builtin_amdgcn_global_load_lds(
                    (const __attribute__((address_space(1))) unsigned*)g,
                    (__attribute__((address_space(3))) unsigned*)&lsb[bc * 512], 16, 0, 0);
            }
        }
        __syncthreads();
        short8_t af[RI], bfg[CI];
        #pragma unroll
        for (int r = 0; r < RI; ++r)
            af[r] = *reinterpret_cast<const short8_t*>(&lsa[(wrow + r * 16 + fr) * BK + fks]);
        #pragma unroll
        for (int c = 0; c < CI; ++c)
            bfg[c] = *reinterpret_cast<const short8_t*>(&lsb[(wcol + c * 16 + fr) * BK + fks]);
        #pragma unroll
        for (int r = 0; r < RI; ++r)
            #pragma unroll
            for (int c = 0; c < CI; ++c)
                acc[r][c] = __builtin_amdgcn_mfma_f32_16x16x32_bf16(af[r], bfg[c], acc[r][c], 0, 0, 0);
    }

    const int rr = (lane >> 4) * 4;
    #pragma unroll
    for (int r = 0; r < RI; ++r)
        #pragma unroll
        for (int c = 0; c < CI; ++c) {
            int n = tileN + wcol + c * 16 + fr;
            float bb = bias[n];
            #pragma unroll
            for (int q = 0; q < 4; ++q) {
                int m = tileM + wrow + r * 16 + rr + q;
                Cout[(size_t)m * N + n] = acc[r][c][q] + bb;
            }
        }
}

__global__ __launch_bounds__(256) void gemm_out_kernel(
    const ushort* __restrict__ ctxb, const ushort* __restrict__ wo,
    const float* __restrict__ bo, float* __restrict__ out)
{
    gemm_out_body<64, 64>(ctxb, wo, bo, out, DD, DD);
}

// ---------------- two-pass attention, 32 q-rows/block, contiguous K/V (R14 body) ----------------
// R14/R16/R17/R18-validated (50 us, absmax 0.0098, VGPR 88). Measured walls:
// - full-unroll pipelining -> VGPR > 128 -> occupancy halves (R11/R15)
// - dropping the y-cache -> recompute adds ~60% issue work, occupancy does not
//   improve (grid only 4 blocks/CU total) (R19, R6)
// => this configuration is the local optimum for this topology.
__global__ __launch_bounds__(256) void attn_kernel(
    const ushort* __restrict__ Qb, const ushort* __restrict__ Kh,
    const ushort* __restrict__ Vt2, const float* __restrict__ E1,
    const float* __restrict__ E3, ushort* __restrict__ ctxb)
{
    __shared__ ushort ycache[4][32][264];  // per-wave bf16 y cache (2 q-tiles); reused as f32 ctx partials
    __shared__ float lbuf[4][4][32];       // [wave][t][qrow 0..31]
    const int wg  = blockIdx.x;
    const int swz = (wg & 7) * 128 + (wg >> 3);   // XCD swizzle (1024 % 8 == 0)
    const int bh  = swz >> 5;
    const int qb  = (swz & 31) * 32;              // 32-row q-block
    const int b = bh >> 4, h = bh & 15;
    const int wave = threadIdx.x >> 6;
    const int lane = threadIdx.x & 63;
    const int fr = lane & 15;
    const int g  = lane >> 4;
    const int fk = g * 8;

    const float wt[4] = {0.008f, 0.032f, 0.16f, 0.8f};   // momentum-collapsed weights

    // Q A-fragments for both 16-row tiles (pre-scaled)
    const ushort* qbase0 = Qb + (size_t)(b * SS + qb + fr) * DD + h * HD;
    const ushort* qbase1 = Qb + (size_t)(b * SS + qb + 16 + fr) * DD + h * HD;
    const short8_t aq0a = *reinterpret_cast<const short8_t*>(qbase0 + fk);
    const short8_t aq1a = *reinterpret_cast<const short8_t*>(qbase0 + 32 + fk);
    const short8_t aq0b = *reinterpret_cast<const short8_t*>(qbase1 + fk);
    const short8_t aq1b = *reinterpret_cast<const short8_t*>(qbase1 + 32 + fk);

    const float* e1h = E1 + bh * SS;
    const float* e3h = E3 + bh * SS;
    const ushort* khead = Kh + (size_t)bh * SS * HD;
    const ushort* vhead = Vt2 + (size_t)bh * (SS / 32) * HD * 32;

    // ---- pass A: shared K frags -> both tiles' QK^T + exp2 + l + y-cache ----
    float lA[4][4] = {}, lB[4][4] = {};
    for (int it = 0; it < 4; ++it) {
        const int k0 = wave * 256 + it * 64;
        #pragma unroll
        for (int n = 0; n < 4; ++n) {
            const ushort* kb = khead + (size_t)(k0 + n * 16 + fr) * HD;
            short8_t bk0 = *reinterpret_cast<const short8_t*>(kb + fk);
            short8_t bk1 = *reinterpret_cast<const short8_t*>(kb + 32 + fk);
            f32x4 za = {0.f, 0.f, 0.f, 0.f};
            f32x4 zb = {0.f, 0.f, 0.f, 0.f};
            za = __builtin_amdgcn_mfma_f32_16x16x32_bf16(aq0a, bk0, za, 0, 0, 0);
            za = __builtin_amdgcn_mfma_f32_16x16x32_bf16(aq1a, bk1, za, 0, 0, 0);
            zb = __builtin_amdgcn_mfma_f32_16x16x32_bf16(aq0b, bk0, zb, 0, 0, 0);
            zb = __builtin_amdgcn_mfma_f32_16x16x32_bf16(aq1b, bk1, zb, 0, 0, 0);
            float e1v = e1h[k0 + n * 16 + fr];
            float e3v = e3h[k0 + n * 16 + fr];
            #pragma unroll
            for (int r = 0; r < 4; ++r) {
                float ya  = EXP2(za[r]);
                float ya2 = ya * ya;
                float ya4 = ya2 * ya2;
                float ya6 = ya4 * ya2;
                lA[0][r] += ya4;
                lA[1][r] += ya4 * ya * e1v;
                lA[2][r] += ya6;
                lA[3][r] += ya6 * ya * e3v;
                ycache[wave][g * 4 + r][it * 64 + n * 16 + fr] = f2bf(ya);
                float yb  = EXP2(zb[r]);
                float yb2 = yb * yb;
                float yb4 = yb2 * yb2;
                float yb6 = yb4 * yb2;
                lB[0][r] += yb4;
                lB[1][r] += yb4 * yb * e1v;
                lB[2][r] += yb6;
                lB[3][r] += yb6 * yb * e3v;
                ycache[wave][16 + g * 4 + r][it * 64 + n * 16 + fr] = f2bf(yb);
            }
        }
    }
    // reduce across the 16 k-col lanes (lane bits 0..3)
    #pragma unroll
    for (int t = 0; t < 4; ++t)
        #pragma unroll
        for (int r = 0; r < 4; ++r) {
            float sa = lA[t][r];
            sa += __shfl_xor(sa, 1);
            sa += __shfl_xor(sa, 2);
            sa += __shfl_xor(sa, 4);
            sa += __shfl_xor(sa, 8);
            lA[t][r] = sa;
            float sb = lB[t][r];
            sb += __shfl_xor(sb, 1);
            sb += __shfl_xor(sb, 2);
            sb += __shfl_xor(sb, 4);
            sb += __shfl_xor(sb, 8);
            lB[t][r] = sb;
        }
    if (fr == 0) {
        #pragma unroll
        for (int t = 0; t < 4; ++t)
            #pragma unroll
            for (int r = 0; r < 4; ++r) {
                lbuf[wave][t][g * 4 + r]      = lA[t][r];
                lbuf[wave][t][16 + g * 4 + r] = lB[t][r];
            }
    }
    __syncthreads();   // orders ycache writes + lbuf for cross-lane pass-B reads

    // per-lane normalized weights for A-frag q-rows fr (tile0) and 16+fr (tile1)
    float wlA[4], wlB[4];
    #pragma unroll
    for (int t = 0; t < 4; ++t) {
        float sa = lbuf[0][t][fr] + lbuf[1][t][fr] + lbuf[2][t][fr] + lbuf[3][t][fr];
        float sb = lbuf[0][t][16 + fr] + lbuf[1][t][16 + fr] + lbuf[2][t][16 + fr] + lbuf[3][t][16 + fr];
        wlA[t] = wt[t] / sa;
        wlB[t] = wt[t] / sb;
    }

    // ---- pass B: shared V frags -> both tiles' normalized P + PV ----
    f32x4 caccA[4] = {}, caccB[4] = {};
    union FragU { short8_t s; unsigned u[4]; };
    for (int it = 0; it < 4; ++it) {
        const int k0 = wave * 256 + it * 64;
        #pragma unroll
        for (int half = 0; half < 2; ++half) {
            short8_t ya8 = *reinterpret_cast<const short8_t*>(
                &ycache[wave][fr][it * 64 + half * 32 + fk]);
            short8_t yb8 = *reinterpret_cast<const short8_t*>(
                &ycache[wave][16 + fr][it * 64 + half * 32 + fk]);
            const float* e1p = e1h + k0 + half * 32 + fk;
            const float* e3p = e3h + k0 + half * 32 + fk;
            float4 e1a = *reinterpret_cast<const float4*>(e1p);
            float4 e1b = *reinterpret_cast<const float4*>(e1p + 4);
            float4 e3a = *reinterpret_cast<const float4*>(e3p);
            float4 e3b = *reinterpret_cast<const float4*>(e3p + 4);
            FragU paA, paB;
            #pragma unroll
            for (int i = 0; i < 4; ++i) {
                float pva[2], pvb[2];
                #pragma unroll
                for (int j = 0; j < 2; ++j) {
                    const int e = 2 * i + j;
                    float e1v = (e < 4) ? ((const float*)&e1a)[e] : ((const float*)&e1b)[e - 4];
                    float e3v = (e < 4) ? ((const float*)&e3a)[e] : ((const float*)&e3b)[e - 4];
                    float ya  = bf2f((ushort)ya8[e]);
                    float ya2 = ya * ya;
                    float ya4 = ya2 * ya2;
                    float t1a = fmaf(ya, wlA[1] * e1v, wlA[0]);
                    float t2a = fmaf(ya, wlA[3] * e3v, wlA[2]);
                    pva[j] = ya4 * fmaf(ya2, t2a, t1a);
                    float yb  = bf2f((ushort)yb8[e]);
                    float yb2 = yb * yb;
                    float yb4 = yb2 * yb2;
                    float t1b = fmaf(yb, wlB[1] * e1v, wlB[0]);
                    float t2b = fmaf(yb, wlB[3] * e3v, wlB[2]);
                    pvb[j] = yb4 * fmaf(yb2, t2b, t1b);
                }
                paA.u[i] = pkbf(pva[0], pva[1]);
                paB.u[i] = pkbf(pvb[0], pvb[1]);
            }
            const ushort* vt = vhead + (size_t)((k0 + half * 32) >> 5) * HD * 32;
            #pragma unroll
            for (int n2 = 0; n2 < 4; ++n2) {
                short8_t v = *reinterpret_cast<const short8_t*>(
                    vt + (n2 * 16 + fr) * 32 + fk);
                caccA[n2] = __builtin_amdgcn_mfma_f32_16x16x32_bf16(paA.s, v, caccA[n2], 0, 0, 0);
                caccB[n2] = __builtin_amdgcn_mfma_f32_16x16x32_bf16(paB.s, v, caccB[n2], 0, 0, 0);
            }
        }
    }

    // ---- epilogue: per-wave partials -> cross-wave sum, both tiles ----
    __syncthreads();   // all ycache reads done; safe to reuse as f32
    float* ctxp = (float*)&ycache[wave][0][0];   // [32][68] f32 view (8704B <= 16896B region)
    #pragma unroll
    for (int n2 = 0; n2 < 4; ++n2)
        #pragma unroll
        for (int q = 0; q < 4; ++q) {
            ctxp[(g * 4 + q) * 68 + n2 * 16 + fr]        = caccA[n2][q];
            ctxp[(16 + g * 4 + q) * 68 + n2 * 16 + fr]   = caccB[n2][q];
        }
    __syncthreads();

    const int d0 = (threadIdx.x & 15) * 4;
    float* base = (float*)&ycache[0][0][0];      // wave stride = 4224 f32
    #pragma unroll
    for (int rr = 0; rr < 2; ++rr) {
        int row = rr * 16 + (threadIdx.x >> 4);
        float4 s0 = *reinterpret_cast<float4*>(base + 0 * 4224 + row * 68 + d0);
        float4 s1 = *reinterpret_cast<float4*>(base + 1 * 4224 + row * 68 + d0);
        float4 s2 = *reinterpret_cast<float4*>(base + 2 * 4224 + row * 68 + d0);
        float4 s3 = *reinterpret_cast<float4*>(base + 3 * 4224 + row * 68 + d0);
        float ox = s0.x + s1.x + s2.x + s3.x;
        float oy = s0.y + s1.y + s2.y + s3.y;
        float oz = s0.z + s1.z + s2.z + s3.z;
        float ow = s0.w + s1.w + s2.w + s3.w;
        uint2 o;
        o.x = pkbf(ox, oy);
        o.y = pkbf(oz, ow);
        size_t off = (size_t)(b * SS + qb + row) * DD + h * HD + d0;
        *reinterpret_cast<uint2*>(ctxb + off) = o;
    }
}

// ---------------- launch ----------------
extern "C" void kernel_launch(void* const* d_in, const int* in_sizes, int n_in,
                              void* d_out, int out_size, void* d_ws, size_t ws_size,
                              hipStream_t stream) {
    const float* x  = (const float*)d_in[0];
    const float* Wq = (const float*)d_in[1];
    const float* bq = (const float*)d_in[2];
    const float* Wk = (const float*)d_in[3];
    const float* bk = (const float*)d_in[4];
    const float* Wv = (const float*)d_in[5];
    const float* bv = (const float*)d_in[6];
    const float* Wo = (const float*)d_in[7];
    const float* bo = (const float*)d_in[8];
    // d_in[9] resonance_bias: per-head row-constant -> cancels in softmax
    const float* pf = (const float*)d_in[10];

    // workspace layout (~28.3 MB)
    ushort* xb   = (ushort*)d_ws;
    ushort* wqb  = xb  + (size_t)2 * 1024 * 1024;
    ushort* wkb  = wqb + (size_t)1024 * 1024;
    ushort* wvb  = wkb + (size_t)1024 * 1024;
    ushort* wob  = wvb + (size_t)1024 * 1024;
    ushort* Qb   = wob + (size_t)1024 * 1024;
    ushort* Kh   = Qb  + (size_t)2 * 1024 * 1024;   // head-major K [bh][j][d]
    ushort* Vt2  = Kh  + (size_t)2 * 1024 * 1024;   // k-tiled V  [bh][j/32][d][j%32]
    ushort* ctxb = Vt2 + (size_t)2 * 1024 * 1024;
    float*  E1p  = (float*)(ctxb + (size_t)2 * 1024 * 1024);
    float*  E3p  = E1p + (size_t)BH * SS;

    // per-iteration constants (match reference f32 casting)
    float ph[4], ctv[4];
    for (int t = 0; t < 4; ++t) {
        double tn = (double)t / 4.0;
        ph[t]  = sinf((float)(2.0 * tn * M_PI + 0.0));
        ctv[t] = (float)((0.8 + 0.2 * (double)t) * 0.125);  // beta_t / sqrt(HD)
    }
    const double LOG2E = 1.44269504088896340736;
    float qscale = (float)(0.025 * LOG2E);  // Q pre-scale: S' = 0.025*log2e*S
    float a1 = ctv[1] * ph[1];   // c1 * sin(pi/2)
    float a3 = ctv[3] * ph[3];   // c3 * sin(3pi/2)

    cvt_all_kernel<<<6144, 256, 0, stream>>>(x, Wq, Wk, Wv, Wo, xb, wqb, wkb, wvb, wob);

    gemm_qkv_fused<<<dim3(16, 32), 256, 0, stream>>>(xb, wqb, wkb, wvb, bq, bk, bv,
                                                     Qb, Kh, Vt2, pf, E1p, E3p,
                                                     qscale, a1, a3);

    attn_kernel<<<1024, 256, 0, stream>>>(Qb, Kh, Vt2, E1p, E3p, ctxb);

    gemm_out_kernel<<<dim3(16, 32), 256, 0, stream>>>(ctxb, wob, bo, (float*)d_out);
}